// Round 11
// baseline (230.049 us; speedup 1.0000x reference)
//
#include <hip/hip_runtime.h>
#include <hip/hip_fp16.h>

// GATConv: N=50000, E=1600000, DIM_IN=256, HEADS=4, DIM_OUT=32 (HC=128)
// R21: D0 kernel deleted (gcur0 via hipMemsetAsync; W transposed f32->f16 on the
//   fly inside proj staging). csr single-pass (regs hold <=12 edges between
//   hist and scatter). agg: scalar off/deg loads via readfirstlane(node).
//   Pipeline: memset; D1 bin||proj; D2 csr(1024t); D3 agg(256t).

#define DIN 256
#define HC 128
#define NH 4
#define NEG 0.2f
#define BCAP 12288
#define LOG2E 1.44269504f

typedef _Float16 half8 __attribute__((ext_vector_type(8)));
typedef _Float16 half2v __attribute__((ext_vector_type(2)));
typedef float f32x4 __attribute__((ext_vector_type(4)));

// ---------------- projection body (MFMA) + fused attention logits ----------------
// Per-sub-block sm layout (18432B): xs [64][40] halves @0 (5120B);
//   Wl [128][40] halves @5120 (10240B); ep [64][136] halves @0 (17408B, reused);
//   attSL @17408 (512B), attDL @17920 (512B).
// tid is the SUB-BLOCK-local thread id (0..255).
// W is read DIRECTLY (fp32 [k][c], coalesced float4) and transposed into LDS
// with f16 convert -- no separate wtrans kernel / Wt buffer.
// NOTE: a_src/a_dst are written PRE-SCALED by log2(e) for agg's exp2f.
__device__ __forceinline__ void proj_body(char* sm, int tid, const float* __restrict__ x,
                                          const float* __restrict__ W,
                                          const float* __restrict__ attS,
                                          const float* __restrict__ attD,
                                          __half* __restrict__ xph,
                                          float* __restrict__ a_src,
                                          float* __restrict__ a_dst, int n, int node0) {
    _Float16* xs = (_Float16*)sm;
    _Float16* Wl = (_Float16*)(sm + 5120);
    _Float16* ep = (_Float16*)sm;
    float* attSL = (float*)(sm + 17408);
    float* attDL = (float*)(sm + 17920);

    const int wave = tid >> 6;
    const int lane = tid & 63;
    const int l15  = lane & 15;
    const int quad = lane >> 4;

    if (tid < 128) attSL[tid] = attS[tid];
    else           attDL[tid - 128] = attD[tid - 128];

    f32x4 acc[8];
#pragma unroll
    for (int ct = 0; ct < 8; ++ct) acc[ct] = (f32x4){0.f, 0.f, 0.f, 0.f};

    for (int kt = 0; kt < DIN; kt += 32) {
        __syncthreads();
#pragma unroll
        for (int r = 0; r < 4; ++r) {
            int idx = tid + r * 256;
            int row = idx >> 4;
            int kp  = idx & 15;
            int gn = node0 + row;
            float2 xv = make_float2(0.f, 0.f);
            if (gn < n) xv = *(const float2*)&x[(size_t)gn * DIN + kt + kp * 2];
            half2v p; p[0] = (_Float16)xv.x; p[1] = (_Float16)xv.y;
            *(half2v*)&xs[row * 40 + kp * 2] = p;
        }
        // W tile [kt..kt+32) x [0..128): coalesced float4 row reads, LDS transpose
#pragma unroll
        for (int r = 0; r < 4; ++r) {
            int id = tid + r * 256;
            int kk = id >> 5;
            int c4 = (id & 31) * 4;
            float4 wv = *(const float4*)&W[(size_t)(kt + kk) * 128 + c4];
            Wl[(c4 + 0) * 40 + kk] = (_Float16)wv.x;
            Wl[(c4 + 1) * 40 + kk] = (_Float16)wv.y;
            Wl[(c4 + 2) * 40 + kk] = (_Float16)wv.z;
            Wl[(c4 + 3) * 40 + kk] = (_Float16)wv.w;
        }
        __syncthreads();
        half8 af = *(const half8*)&xs[(wave * 16 + l15) * 40 + quad * 8];
#pragma unroll
        for (int ct = 0; ct < 8; ++ct) {
            half8 bf = *(const half8*)&Wl[(ct * 16 + l15) * 40 + quad * 8];
            acc[ct] = __builtin_amdgcn_mfma_f32_16x16x32_f16(af, bf, acc[ct], 0, 0, 0);
        }
    }
    __syncthreads();
#pragma unroll
    for (int ct = 0; ct < 8; ++ct)
#pragma unroll
        for (int r = 0; r < 4; ++r) {
            int row = wave * 16 + quad * 4 + r;
            ep[row * 136 + ct * 16 + l15] = (_Float16)acc[ct][r];
        }
    __syncthreads();
    {
        int row = tid >> 2, ch = tid & 3;
        int node = node0 + row;
        if (node < n) {
            const uint4* s = (const uint4*)&ep[row * 136 + ch * 32];
            uint4* d = (uint4*)&xph[(size_t)node * HC + ch * 32];
            d[0] = s[0]; d[1] = s[1]; d[2] = s[2]; d[3] = s[3];
        }
    }
    {
        int nl = tid >> 2, h = tid & 3;
        int node = node0 + nl;
        if (node < n) {
            float ps = 0.f, pd = 0.f;
            const _Float16* er = &ep[nl * 136 + h * 32];
#pragma unroll
            for (int c = 0; c < 32; ++c) {
                float v = (float)er[c];
                ps += v * attSL[h * 32 + c];
                pd += v * attDL[h * 32 + c];
            }
            a_src[node * NH + h] = ps * LOG2E;   // pre-scale for exp2 in agg
            a_dst[node * NH + h] = pd * LOG2E;
        }
    }
}

// ---------------- D1: bin (fixed-capacity buckets, self-allocating) || proj ----------------
// blocks [0,ech): bin, 512t, 8 edges/thread.  blocks [ech,..): 2x proj sub-tiles.
__global__ __launch_bounds__(512) void k_bin_proj(const int* __restrict__ ei,
                                                  int* __restrict__ gcur0,
                                                  unsigned* __restrict__ binned,
                                                  const float* __restrict__ x,
                                                  const float* __restrict__ W,
                                                  const float* __restrict__ attS,
                                                  const float* __restrict__ attD,
                                                  __half* __restrict__ xph,
                                                  float* __restrict__ a_src,
                                                  float* __restrict__ a_dst,
                                                  int e, int n, int ech) {
    __shared__ __attribute__((aligned(16))) char sm[36864];
    if ((int)blockIdx.x < ech) {
        int* h     = (int*)sm;
        int* rbase = (int*)(sm + 1024);
        const int tid = threadIdx.x;
        if (tid < 256) h[tid] = 0;
        __syncthreads();
        const int base = blockIdx.x * 4096;
        unsigned pk[8];
        int bk[8];
#pragma unroll
        for (int j = 0; j < 8; ++j) {
            int i = base + j * 512 + tid;
            bk[j] = -1;
            if (i < e) {
                int src = ei[i];
                int dst = ei[e + i];
                if ((unsigned)dst < (unsigned)n && (unsigned)src < (unsigned)n) {
                    bk[j] = dst >> 8;
                    pk[j] = ((unsigned)(dst & 255) << 16) | (unsigned)src;
                    atomicAdd(&h[bk[j]], 1);
                }
            }
        }
        __syncthreads();
        if (tid < 256) {
            if (h[tid]) rbase[tid] = atomicAdd(&gcur0[tid], h[tid]);
            h[tid] = 0;
        }
        __syncthreads();
#pragma unroll
        for (int j = 0; j < 8; ++j) {
            if (bk[j] >= 0) {
                int p = atomicAdd(&h[bk[j]], 1);
                int pib = rbase[bk[j]] + p;
                if (pib < BCAP) binned[(size_t)bk[j] * BCAP + pib] = pk[j];
            }
        }
    } else {
        const int sub = threadIdx.x >> 8;       // 0 or 1
        const int tid = threadIdx.x & 255;
        const int tile = ((int)blockIdx.x - ech) * 2 + sub;
        proj_body(sm + sub * 18432, tid, x, W, attS, attD, xph, a_src, a_dst, n, tile * 64);
    }
}

// ---------------- D2: per-bucket counting sort, single pass over binned ----------------
// bucket b occupies binned[b*BCAP .. b*BCAP+cnt_b); each thread keeps its <=12
// entries in registers between the histogram and scatter phases.
__global__ __launch_bounds__(1024) void k_csr(const unsigned* __restrict__ binned,
                                              const int* __restrict__ gcnt,
                                              int* __restrict__ off,
                                              int* __restrict__ deg,
                                              unsigned short* __restrict__ srt,
                                              int n) {
    __shared__ int cnt[256], buf[256], cur[256];
    const int tid = threadIdx.x;
    const int b = blockIdx.x;
    if (tid < 256) { buf[tid] = min(gcnt[tid], BCAP); cnt[tid] = 0; }
    __syncthreads();
    for (int s = 1; s < 256; s <<= 1) {
        int t = (tid < 256 && tid >= s) ? buf[tid - s] : 0;
        __syncthreads();
        if (tid < 256) buf[tid] += t;
        __syncthreads();
    }
    const int cb = min(gcnt[b], BCAP);
    const int excl = buf[b] - cb;                // exclusive scan of counts
    const int pgbase = ((excl + 31) & ~31) + b * 8192;
    const int kb = b * BCAP;
    const int ke = kb + cb;
    __syncthreads();                             // buf reads done before reuse
    unsigned pk[12];                             // BCAP/1024 = 12 max per thread
#pragma unroll
    for (int j = 0; j < 12; ++j) {
        int i = kb + j * 1024 + tid;
        pk[j] = 0xFFFFFFFFu;                     // sentinel (valid pv < 0x01000000)
        if (i < ke) {
            pk[j] = binned[i];
            atomicAdd(&cnt[pk[j] >> 16], 1);
        }
    }
    __syncthreads();
    int v = 0;
    if (tid < 256) { v = cnt[tid]; buf[tid] = (v + 31) & ~31; }
    __syncthreads();
    for (int s = 1; s < 256; s <<= 1) {
        int t = (tid < 256 && tid >= s) ? buf[tid - s] : 0;
        __syncthreads();
        if (tid < 256) buf[tid] += t;
        __syncthreads();
    }
    if (tid < 256) {
        const int myoff = pgbase + buf[tid] - ((v + 31) & ~31);   // 32-aligned
        const int node = b * 256 + tid;
        if (node < n) { off[node] = myoff; deg[node] = v; }
        cur[tid] = myoff;
    }
    __syncthreads();
#pragma unroll
    for (int j = 0; j < 12; ++j) {
        if (pk[j] != 0xFFFFFFFFu) {
            int nl = pk[j] >> 16;
            int pos = atomicAdd(&cur[nl], 1);
            srt[pos] = (unsigned short)(pk[j] & 0xFFFFu);
        }
    }
}

// ---------------- D3: aggregate ----------------
// 4 edge-groups x 16 lanes; lane covers channels [l*8, l*8+8) via 16B gather.
// BATCH=4; aligned ushort4 index loads; predicated tail. 256t blocks.
// u32 addressing (saddr loads); node in SGPR via readfirstlane -> off/deg scalar.
__global__ __launch_bounds__(256) void agg_kernel(const __half* __restrict__ xph,
                                                  const float* __restrict__ a_src,
                                                  const float* __restrict__ a_dst,
                                                  const int* __restrict__ off,
                                                  const int* __restrict__ deg,
                                                  const unsigned short* __restrict__ srt,
                                                  const float* __restrict__ bias,
                                                  float* __restrict__ out, int n) {
    int node_ = (blockIdx.x * blockDim.x + threadIdx.x) >> 6;
    if (node_ >= n) return;
    const int node = __builtin_amdgcn_readfirstlane(node_);   // wave-uniform -> SGPR
    const int lane = threadIdx.x & 63;
    const int g = lane >> 4;
    const unsigned l = (unsigned)(lane & 15);
    const unsigned h = l >> 2;
    const unsigned lo8 = l * 8u;                 // channel base for this lane

    const float ad = a_dst[((unsigned)node << 2) + h];

    float acc[8];
#pragma unroll
    for (int c = 0; c < 8; ++c) acc[c] = 0.f;
    float den = 0.f;

    if (g == 0) {   // self loop
        float t = a_src[((unsigned)node << 2) + h] + ad;
        float s = exp2f(fmaxf(t, NEG * t));
        half8 xv = *(const half8*)&xph[((unsigned)node << 7) + lo8];
#pragma unroll
        for (int c = 0; c < 8; ++c) acc[c] = s * (float)xv[c];
        den = s;
    }

    const int kb = off[node];
    const int ke = kb + deg[node];
    int k0 = kb;
    for (; k0 + 16 <= ke; k0 += 16) {
        const unsigned kg = (unsigned)(k0 + g * 4);
        const ushort4 s4 = *(const ushort4*)&srt[kg];
        unsigned sv[4] = {s4.x, s4.y, s4.z, s4.w};
        float asv[4];
        half8 hv[4];
#pragma unroll
        for (int j = 0; j < 4; ++j) asv[j] = a_src[(sv[j] << 2) + h];
#pragma unroll
        for (int j = 0; j < 4; ++j)
            hv[j] = *(const half8*)&xph[(sv[j] << 7) + lo8];
#pragma unroll
        for (int j = 0; j < 4; ++j) {
            float t = asv[j] + ad;
            const float s = exp2f(fmaxf(t, NEG * t));
#pragma unroll
            for (int c = 0; c < 8; ++c) acc[c] += s * (float)hv[j][c];
            den += s;
        }
    }
    if (k0 < ke) {   // predicated tail; srt reads stay in padded region
        const unsigned kg = (unsigned)(k0 + g * 4);
        const ushort4 s4 = *(const ushort4*)&srt[kg];
        const unsigned sv[4] = {s4.x, s4.y, s4.z, s4.w};
#pragma unroll
        for (int j = 0; j < 4; ++j) {
            if ((int)kg + j < ke) {
                float t = a_src[(sv[j] << 2) + h] + ad;
                const float s = exp2f(fmaxf(t, NEG * t));
                const half8 hv = *(const half8*)&xph[(sv[j] << 7) + lo8];
#pragma unroll
                for (int c = 0; c < 8; ++c) acc[c] += s * (float)hv[c];
                den += s;
            }
        }
    }

#pragma unroll
    for (int c = 0; c < 8; ++c) acc[c] += __shfl_xor(acc[c], 16, 64);
    den += __shfl_xor(den, 16, 64);
#pragma unroll
    for (int c = 0; c < 8; ++c) acc[c] += __shfl_xor(acc[c], 32, 64);
    den += __shfl_xor(den, 32, 64);

    if (lane < 16) {
        const float inv = 1.0f / den;
        const float4* b4 = (const float4*)&bias[lo8];
        float4 o0, o1;
        o0.x = acc[0] * inv + b4[0].x;
        o0.y = acc[1] * inv + b4[0].y;
        o0.z = acc[2] * inv + b4[0].z;
        o0.w = acc[3] * inv + b4[0].w;
        o1.x = acc[4] * inv + b4[1].x;
        o1.y = acc[5] * inv + b4[1].y;
        o1.z = acc[6] * inv + b4[1].z;
        o1.w = acc[7] * inv + b4[1].w;
        float4* d = (float4*)&out[((unsigned)node << 7) + lo8];
        d[0] = o0;
        d[1] = o1;
    }
}

// ---------------- launch ----------------
extern "C" void kernel_launch(void* const* d_in, const int* in_sizes, int n_in,
                              void* d_out, int out_size, void* d_ws, size_t ws_size,
                              hipStream_t stream) {
    if (n_in < 6 || !d_out || !d_ws) return;
    const float* x    = (const float*)d_in[0];
    const int*   ei   = (const int*)d_in[1];
    const float* W    = (const float*)d_in[2];
    const float* attS = (const float*)d_in[3];
    const float* attD = (const float*)d_in[4];
    const float* bias = (const float*)d_in[5];
    float* out = (float*)d_out;

    const int N = in_sizes[0] / DIN;
    const int E = in_sizes[1] / 2;
    if (N <= 0 || E <= 0) return;
    const int NBUCK = (N + 255) >> 8;
    if (NBUCK > 256 || N > 65536) return;   // src fits 16 bits; 256-bucket scheme

    char* ws = (char*)d_ws;
    size_t off_b = 0;
    auto carve = [&](size_t bytes) {
        size_t p = off_b;
        off_b = (off_b + bytes + 255) & ~(size_t)255;
        return (void*)(ws + p);
    };
    __half*         xph    = (__half*)carve((size_t)N * HC * 2);
    float*          a_src  = (float*)carve((size_t)N * NH * 4);
    float*          a_dst  = (float*)carve((size_t)N * NH * 4);
    int*            gz     = (int*)carve(512 * 4);        // gcur0[256] (+spare)
    unsigned*       binned = (unsigned*)carve((size_t)NBUCK * BCAP * 4);
    int*            offp   = (int*)carve((size_t)N * 4);
    int*            degp   = (int*)carve((size_t)N * 4);
    unsigned short* srt    = (unsigned short*)carve(((size_t)E + (size_t)NBUCK * 8192 + 64) * 2);
    (void)out_size;
    if (off_b > ws_size) return;

    int* gcur0 = gz;

    const int ECH = (E + 4095) / 4096;      // bin blocks: 4096 edges each @512t
    const int PB  = (N + 63) / 64;          // 64-node proj tiles
    const int PBH = (PB + 1) / 2;           // proj blocks (2 tiles each)

    hipMemsetAsync(gcur0, 0, 256 * sizeof(int), stream);
    k_bin_proj<<<ECH + PBH, 512, 0, stream>>>(ei, gcur0, binned, x, W, attS, attD,
                                              xph, a_src, a_dst, E, N, ECH);
    k_csr<<<NBUCK, 1024, 0, stream>>>(binned, gcur0, offp, degp, srt, N);
    agg_kernel<<<(N * 64 + 255) / 256, 256, 0, stream>>>(xph, a_src, a_dst,
                                                         offp, degp, srt, bias, out, N);
}

// Round 12
// 214.467 us; speedup vs baseline: 1.0727x; 1.0727x over previous
//
#include <hip/hip_runtime.h>
#include <hip/hip_fp16.h>

// GATConv: N=50000, E=1600000, DIM_IN=256, HEADS=4, DIM_OUT=32 (HC=128)
// R22: revert R21's in-proj W transpose (16-way LDS bank conflict, 1.4e7 cycles,
//   +13us) -> restore R20 k_zero_wtrans + Wt half8 staging (conflict-free).
//   Keep R21's single-pass csr and agg (u32 addr + readfirstlane + exp2f).
//   Pipeline: D0 zero||wtrans; D1 bin||proj; D2 csr(1024t); D3 agg(256t).

#define DIN 256
#define HC 128
#define NH 4
#define NEG 0.2f
#define BCAP 12288
#define LOG2E 1.44269504f

typedef _Float16 half8 __attribute__((ext_vector_type(8)));
typedef _Float16 half2v __attribute__((ext_vector_type(2)));
typedef float f32x4 __attribute__((ext_vector_type(4)));

// ---------------- projection body (MFMA) + fused attention logits ----------------
// Per-sub-block sm layout (18432B): xs [64][40] halves @0 (5120B);
//   Wl [128][40] halves @5120 (10240B); ep [64][136] halves @0 (17408B, reused);
//   attSL @17408 (512B), attDL @17920 (512B).
// tid is the SUB-BLOCK-local thread id (0..255).
// NOTE: a_src/a_dst are written PRE-SCALED by log2(e) for agg's exp2f.
__device__ __forceinline__ void proj_body(char* sm, int tid, const float* __restrict__ x,
                                          const _Float16* __restrict__ Wt,
                                          const float* __restrict__ attS,
                                          const float* __restrict__ attD,
                                          __half* __restrict__ xph,
                                          float* __restrict__ a_src,
                                          float* __restrict__ a_dst, int n, int node0) {
    _Float16* xs = (_Float16*)sm;
    _Float16* Wl = (_Float16*)(sm + 5120);
    _Float16* ep = (_Float16*)sm;
    float* attSL = (float*)(sm + 17408);
    float* attDL = (float*)(sm + 17920);

    const int wave = tid >> 6;
    const int lane = tid & 63;
    const int l15  = lane & 15;
    const int quad = lane >> 4;

    if (tid < 128) attSL[tid] = attS[tid];
    else           attDL[tid - 128] = attD[tid - 128];

    f32x4 acc[8];
#pragma unroll
    for (int ct = 0; ct < 8; ++ct) acc[ct] = (f32x4){0.f, 0.f, 0.f, 0.f};

    for (int kt = 0; kt < DIN; kt += 32) {
        __syncthreads();
#pragma unroll
        for (int r = 0; r < 4; ++r) {
            int idx = tid + r * 256;
            int row = idx >> 4;
            int kp  = idx & 15;
            int gn = node0 + row;
            float2 xv = make_float2(0.f, 0.f);
            if (gn < n) xv = *(const float2*)&x[(size_t)gn * DIN + kt + kp * 2];
            half2v p; p[0] = (_Float16)xv.x; p[1] = (_Float16)xv.y;
            *(half2v*)&xs[row * 40 + kp * 2] = p;
        }
#pragma unroll
        for (int r = 0; r < 2; ++r) {
            int id = tid + r * 256;
            int c = id >> 2;
            int q = id & 3;
            half8 wv = *(const half8*)&Wt[(size_t)c * 256 + kt + q * 8];
            *(half8*)&Wl[c * 40 + q * 8] = wv;
        }
        __syncthreads();
        half8 af = *(const half8*)&xs[(wave * 16 + l15) * 40 + quad * 8];
#pragma unroll
        for (int ct = 0; ct < 8; ++ct) {
            half8 bf = *(const half8*)&Wl[(ct * 16 + l15) * 40 + quad * 8];
            acc[ct] = __builtin_amdgcn_mfma_f32_16x16x32_f16(af, bf, acc[ct], 0, 0, 0);
        }
    }
    __syncthreads();
#pragma unroll
    for (int ct = 0; ct < 8; ++ct)
#pragma unroll
        for (int r = 0; r < 4; ++r) {
            int row = wave * 16 + quad * 4 + r;
            ep[row * 136 + ct * 16 + l15] = (_Float16)acc[ct][r];
        }
    __syncthreads();
    {
        int row = tid >> 2, ch = tid & 3;
        int node = node0 + row;
        if (node < n) {
            const uint4* s = (const uint4*)&ep[row * 136 + ch * 32];
            uint4* d = (uint4*)&xph[(size_t)node * HC + ch * 32];
            d[0] = s[0]; d[1] = s[1]; d[2] = s[2]; d[3] = s[3];
        }
    }
    {
        int nl = tid >> 2, h = tid & 3;
        int node = node0 + nl;
        if (node < n) {
            float ps = 0.f, pd = 0.f;
            const _Float16* er = &ep[nl * 136 + h * 32];
#pragma unroll
            for (int c = 0; c < 32; ++c) {
                float v = (float)er[c];
                ps += v * attSL[h * 32 + c];
                pd += v * attDL[h * 32 + c];
            }
            a_src[node * NH + h] = ps * LOG2E;   // pre-scale for exp2 in agg
            a_dst[node * NH + h] = pd * LOG2E;
        }
    }
}

// ---------------- D0: zero gcur0 || wtrans ----------------
__global__ __launch_bounds__(256) void k_zero_wtrans(int* __restrict__ gz,
                                                     const float* __restrict__ W,
                                                     _Float16* __restrict__ Wt) {
    const int b = blockIdx.x;
    if (b < 2) {
        gz[b * 256 + threadIdx.x] = 0;
    } else {
        int i = (b - 2) * 256 + threadIdx.x;
        int k = i >> 7, c = i & 127;
        Wt[c * 256 + k] = (_Float16)W[i];
    }
}

// ---------------- D1: bin (fixed-capacity buckets, self-allocating) || proj ----------------
// blocks [0,ech): bin, 512t, 8 edges/thread.  blocks [ech,..): 2x proj sub-tiles.
__global__ __launch_bounds__(512) void k_bin_proj(const int* __restrict__ ei,
                                                  int* __restrict__ gcur0,
                                                  unsigned* __restrict__ binned,
                                                  const float* __restrict__ x,
                                                  const _Float16* __restrict__ Wt,
                                                  const float* __restrict__ attS,
                                                  const float* __restrict__ attD,
                                                  __half* __restrict__ xph,
                                                  float* __restrict__ a_src,
                                                  float* __restrict__ a_dst,
                                                  int e, int n, int ech) {
    __shared__ __attribute__((aligned(16))) char sm[36864];
    if ((int)blockIdx.x < ech) {
        int* h     = (int*)sm;
        int* rbase = (int*)(sm + 1024);
        const int tid = threadIdx.x;
        if (tid < 256) h[tid] = 0;
        __syncthreads();
        const int base = blockIdx.x * 4096;
        unsigned pk[8];
        int bk[8];
#pragma unroll
        for (int j = 0; j < 8; ++j) {
            int i = base + j * 512 + tid;
            bk[j] = -1;
            if (i < e) {
                int src = ei[i];
                int dst = ei[e + i];
                if ((unsigned)dst < (unsigned)n && (unsigned)src < (unsigned)n) {
                    bk[j] = dst >> 8;
                    pk[j] = ((unsigned)(dst & 255) << 16) | (unsigned)src;
                    atomicAdd(&h[bk[j]], 1);
                }
            }
        }
        __syncthreads();
        if (tid < 256) {
            if (h[tid]) rbase[tid] = atomicAdd(&gcur0[tid], h[tid]);
            h[tid] = 0;
        }
        __syncthreads();
#pragma unroll
        for (int j = 0; j < 8; ++j) {
            if (bk[j] >= 0) {
                int p = atomicAdd(&h[bk[j]], 1);
                int pib = rbase[bk[j]] + p;
                if (pib < BCAP) binned[(size_t)bk[j] * BCAP + pib] = pk[j];
            }
        }
    } else {
        const int sub = threadIdx.x >> 8;       // 0 or 1
        const int tid = threadIdx.x & 255;
        const int tile = ((int)blockIdx.x - ech) * 2 + sub;
        proj_body(sm + sub * 18432, tid, x, Wt, attS, attD, xph, a_src, a_dst, n, tile * 64);
    }
}

// ---------------- D2: per-bucket counting sort, single pass over binned ----------------
// bucket b occupies binned[b*BCAP .. b*BCAP+cnt_b); each thread keeps its <=12
// entries in registers between the histogram and scatter phases.
__global__ __launch_bounds__(1024) void k_csr(const unsigned* __restrict__ binned,
                                              const int* __restrict__ gcnt,
                                              int* __restrict__ off,
                                              int* __restrict__ deg,
                                              unsigned short* __restrict__ srt,
                                              int n) {
    __shared__ int cnt[256], buf[256], cur[256];
    const int tid = threadIdx.x;
    const int b = blockIdx.x;
    if (tid < 256) { buf[tid] = min(gcnt[tid], BCAP); cnt[tid] = 0; }
    __syncthreads();
    for (int s = 1; s < 256; s <<= 1) {
        int t = (tid < 256 && tid >= s) ? buf[tid - s] : 0;
        __syncthreads();
        if (tid < 256) buf[tid] += t;
        __syncthreads();
    }
    const int cb = min(gcnt[b], BCAP);
    const int excl = buf[b] - cb;                // exclusive scan of counts
    const int pgbase = ((excl + 31) & ~31) + b * 8192;
    const int kb = b * BCAP;
    const int ke = kb + cb;
    __syncthreads();                             // buf reads done before reuse
    unsigned pk[12];                             // BCAP/1024 = 12 max per thread
#pragma unroll
    for (int j = 0; j < 12; ++j) {
        int i = kb + j * 1024 + tid;
        pk[j] = 0xFFFFFFFFu;                     // sentinel (valid pv < 0x01000000)
        if (i < ke) {
            pk[j] = binned[i];
            atomicAdd(&cnt[pk[j] >> 16], 1);
        }
    }
    __syncthreads();
    int v = 0;
    if (tid < 256) { v = cnt[tid]; buf[tid] = (v + 31) & ~31; }
    __syncthreads();
    for (int s = 1; s < 256; s <<= 1) {
        int t = (tid < 256 && tid >= s) ? buf[tid - s] : 0;
        __syncthreads();
        if (tid < 256) buf[tid] += t;
        __syncthreads();
    }
    if (tid < 256) {
        const int myoff = pgbase + buf[tid] - ((v + 31) & ~31);   // 32-aligned
        const int node = b * 256 + tid;
        if (node < n) { off[node] = myoff; deg[node] = v; }
        cur[tid] = myoff;
    }
    __syncthreads();
#pragma unroll
    for (int j = 0; j < 12; ++j) {
        if (pk[j] != 0xFFFFFFFFu) {
            int nl = pk[j] >> 16;
            int pos = atomicAdd(&cur[nl], 1);
            srt[pos] = (unsigned short)(pk[j] & 0xFFFFu);
        }
    }
}

// ---------------- D3: aggregate ----------------
// 4 edge-groups x 16 lanes; lane covers channels [l*8, l*8+8) via 16B gather.
// BATCH=4; aligned ushort4 index loads; predicated tail. 256t blocks.
// u32 addressing (saddr loads); node in SGPR via readfirstlane -> off/deg scalar.
__global__ __launch_bounds__(256) void agg_kernel(const __half* __restrict__ xph,
                                                  const float* __restrict__ a_src,
                                                  const float* __restrict__ a_dst,
                                                  const int* __restrict__ off,
                                                  const int* __restrict__ deg,
                                                  const unsigned short* __restrict__ srt,
                                                  const float* __restrict__ bias,
                                                  float* __restrict__ out, int n) {
    int node_ = (blockIdx.x * blockDim.x + threadIdx.x) >> 6;
    if (node_ >= n) return;
    const int node = __builtin_amdgcn_readfirstlane(node_);   // wave-uniform -> SGPR
    const int lane = threadIdx.x & 63;
    const int g = lane >> 4;
    const unsigned l = (unsigned)(lane & 15);
    const unsigned h = l >> 2;
    const unsigned lo8 = l * 8u;                 // channel base for this lane

    const float ad = a_dst[((unsigned)node << 2) + h];

    float acc[8];
#pragma unroll
    for (int c = 0; c < 8; ++c) acc[c] = 0.f;
    float den = 0.f;

    if (g == 0) {   // self loop
        float t = a_src[((unsigned)node << 2) + h] + ad;
        float s = exp2f(fmaxf(t, NEG * t));
        half8 xv = *(const half8*)&xph[((unsigned)node << 7) + lo8];
#pragma unroll
        for (int c = 0; c < 8; ++c) acc[c] = s * (float)xv[c];
        den = s;
    }

    const int kb = off[node];
    const int ke = kb + deg[node];
    int k0 = kb;
    for (; k0 + 16 <= ke; k0 += 16) {
        const unsigned kg = (unsigned)(k0 + g * 4);
        const ushort4 s4 = *(const ushort4*)&srt[kg];
        unsigned sv[4] = {s4.x, s4.y, s4.z, s4.w};
        float asv[4];
        half8 hv[4];
#pragma unroll
        for (int j = 0; j < 4; ++j) asv[j] = a_src[(sv[j] << 2) + h];
#pragma unroll
        for (int j = 0; j < 4; ++j)
            hv[j] = *(const half8*)&xph[(sv[j] << 7) + lo8];
#pragma unroll
        for (int j = 0; j < 4; ++j) {
            float t = asv[j] + ad;
            const float s = exp2f(fmaxf(t, NEG * t));
#pragma unroll
            for (int c = 0; c < 8; ++c) acc[c] += s * (float)hv[j][c];
            den += s;
        }
    }
    if (k0 < ke) {   // predicated tail; srt reads stay in padded region
        const unsigned kg = (unsigned)(k0 + g * 4);
        const ushort4 s4 = *(const ushort4*)&srt[kg];
        const unsigned sv[4] = {s4.x, s4.y, s4.z, s4.w};
#pragma unroll
        for (int j = 0; j < 4; ++j) {
            if ((int)kg + j < ke) {
                float t = a_src[(sv[j] << 2) + h] + ad;
                const float s = exp2f(fmaxf(t, NEG * t));
                const half8 hv = *(const half8*)&xph[(sv[j] << 7) + lo8];
#pragma unroll
                for (int c = 0; c < 8; ++c) acc[c] += s * (float)hv[c];
                den += s;
            }
        }
    }

#pragma unroll
    for (int c = 0; c < 8; ++c) acc[c] += __shfl_xor(acc[c], 16, 64);
    den += __shfl_xor(den, 16, 64);
#pragma unroll
    for (int c = 0; c < 8; ++c) acc[c] += __shfl_xor(acc[c], 32, 64);
    den += __shfl_xor(den, 32, 64);

    if (lane < 16) {
        const float inv = 1.0f / den;
        const float4* b4 = (const float4*)&bias[lo8];
        float4 o0, o1;
        o0.x = acc[0] * inv + b4[0].x;
        o0.y = acc[1] * inv + b4[0].y;
        o0.z = acc[2] * inv + b4[0].z;
        o0.w = acc[3] * inv + b4[0].w;
        o1.x = acc[4] * inv + b4[1].x;
        o1.y = acc[5] * inv + b4[1].y;
        o1.z = acc[6] * inv + b4[1].z;
        o1.w = acc[7] * inv + b4[1].w;
        float4* d = (float4*)&out[((unsigned)node << 7) + lo8];
        d[0] = o0;
        d[1] = o1;
    }
}

// ---------------- launch ----------------
extern "C" void kernel_launch(void* const* d_in, const int* in_sizes, int n_in,
                              void* d_out, int out_size, void* d_ws, size_t ws_size,
                              hipStream_t stream) {
    if (n_in < 6 || !d_out || !d_ws) return;
    const float* x    = (const float*)d_in[0];
    const int*   ei   = (const int*)d_in[1];
    const float* W    = (const float*)d_in[2];
    const float* attS = (const float*)d_in[3];
    const float* attD = (const float*)d_in[4];
    const float* bias = (const float*)d_in[5];
    float* out = (float*)d_out;

    const int N = in_sizes[0] / DIN;
    const int E = in_sizes[1] / 2;
    if (N <= 0 || E <= 0) return;
    const int NBUCK = (N + 255) >> 8;
    if (NBUCK > 256 || N > 65536) return;   // src fits 16 bits; 256-bucket scheme

    char* ws = (char*)d_ws;
    size_t off_b = 0;
    auto carve = [&](size_t bytes) {
        size_t p = off_b;
        off_b = (off_b + bytes + 255) & ~(size_t)255;
        return (void*)(ws + p);
    };
    __half*         xph    = (__half*)carve((size_t)N * HC * 2);
    _Float16*       Wt     = (_Float16*)carve((size_t)HC * DIN * 2);
    float*          a_src  = (float*)carve((size_t)N * NH * 4);
    float*          a_dst  = (float*)carve((size_t)N * NH * 4);
    int*            gz     = (int*)carve(512 * 4);        // gcur0[256] (+spare)
    unsigned*       binned = (unsigned*)carve((size_t)NBUCK * BCAP * 4);
    int*            offp   = (int*)carve((size_t)N * 4);
    int*            degp   = (int*)carve((size_t)N * 4);
    unsigned short* srt    = (unsigned short*)carve(((size_t)E + (size_t)NBUCK * 8192 + 64) * 2);
    (void)out_size;
    if (off_b > ws_size) return;

    int* gcur0 = gz;

    const int ECH = (E + 4095) / 4096;      // bin blocks: 4096 edges each @512t
    const int PB  = (N + 63) / 64;          // 64-node proj tiles
    const int PBH = (PB + 1) / 2;           // proj blocks (2 tiles each)

    k_zero_wtrans<<<2 + 128, 256, 0, stream>>>(gz, W, Wt);
    k_bin_proj<<<ECH + PBH, 512, 0, stream>>>(ei, gcur0, binned, x, Wt, attS, attD,
                                              xph, a_src, a_dst, E, N, ECH);
    k_csr<<<NBUCK, 1024, 0, stream>>>(binned, gcur0, offp, degp, srt, N);
    agg_kernel<<<(N * 64 + 255) / 256, 256, 0, stream>>>(xph, a_src, a_dst,
                                                         offp, degp, srt, bias, out, N);
}